// Round 6
// baseline (130.804 us; speedup 1.0000x reference)
//
#include <hip/hip_runtime.h>
#include <hip/hip_bf16.h>
#include <stdint.h>

// KAN layer: out[b,o] = sum_{i,k} basis(tanh(x[b,i]))[k] * coeffs[o,i,k]
// GEMM M=8192, N=512, K=4096.  cvt coeffs->Bt bf16 (ws) ; basis(x)->A (ws) ;
// gemm(A,Bt)->out.
// R12 post-mortem: de-conflicted 32x32 swizzle was time-neutral -> conflicts
// were hidden; the wall is LDS VOLUME: frag-read bytes/MFMA = (rows+cols)/
// (rows*cols) of the wave tile.  64x64 tile -> 1.0 reads/MFMA -> 6MB/CU
// (4MB reads + 2MB staging) ~ 72kcy at 85B/cy ~ the measured 42us.
// R13: wave-tile 128x64 (4x2 frags of 32x32) -> ratio 0.75 -> 5MB/CU.
// Block 128x128, 8 waves = 4 K-groups x 2 waves, BK=32, LDS = 4grp x dbuf x
// (A 8K + B 8K) = 128KB.  Same R7 sync skeleton: 32 iters, one __syncthreads
// per iter, stage it+1 under compute of it via global_load_lds.
// BK=32 rows are 64B -> new swizzle: 2 rows per 128B line,
//   q = ((r&1)<<2 | c) ^ ((r>>1)&7) ^ (((r>>4)&1)<<2)
// quartet {l,l+16,l+32,l+48} -> slots {q,q^4,q^1,q^5} distinct; every
// 16-lane phase hits all 8 slots exactly 2x (free).  Involution -> staging
// source pre-swizzled, LDS dest linear (rule #21).
// Epilogue: 2-round 4-way tree reduce in LDS (groups 1,3 park; 0,2 add;
// 2 parks; 0 adds + stores).

#define M_TOTAL 8192
#define N_DIM   512
#define K_DIM   4096
#define BM 128
#define BN 128
#define BK 32
#define NGRP 4
#define NT_G 32             // iters per group: (4096/4)/32
#define GRP_LDS 32768       // per-group arena: 2 buffers x 16KB
#define BUF_SZ 16384        // one buffer: A 8KB + B 8KB

typedef __attribute__((ext_vector_type(8))) short short8;    // 8 x bf16
typedef __attribute__((ext_vector_type(4))) float f32x4;
typedef __attribute__((ext_vector_type(16))) float f32x16;

typedef const __attribute__((address_space(1))) uint32_t ga_u32;
typedef __attribute__((address_space(3))) uint32_t ls_u32;

__device__ __forceinline__ void gload_lds16(const void* g, void* l) {
  // async global->LDS, 16B/lane; LDS dest = wave-uniform base + lane*16
  __builtin_amdgcn_global_load_lds((ga_u32*)(uintptr_t)g,
                                   (ls_u32*)(uint32_t)(uintptr_t)l, 16, 0, 0);
}

__device__ __forceinline__ uint32_t f2bf(float f) {
  uint32_t u = __builtin_bit_cast(uint32_t, f);
  return (u + 0x7FFFu + ((u >> 16) & 1u)) >> 16;
}

// BK=32 slot swizzle: logical (row r, 16B-chunk c in 0..3) -> phys slot q in
// the 8-slot 128B line L = r>>1.  XOR involution in the 3-bit slot space.
__device__ __forceinline__ int swz32(int r, int c) {
  return (((r & 1) << 2) | c) ^ ((r >> 1) & 7) ^ (((r >> 4) & 1) << 2);
}

// cardinal cubic B-spline on uniform knots h=2/11; t=tanh(x) in (-1,1).
// 8 basis slots as 4xu32 packed bf16: w0..w3 land at slots c-3..c, rest 0.
__device__ __forceinline__ void basis_slots(float xv, uint32_t o[4]) {
  xv = fminf(15.f, fmaxf(-15.f, xv));
  float e  = __expf(2.0f * xv);
  float t  = (e - 1.0f) * __builtin_amdgcn_rcpf(e + 1.0f);
  float uf = (t + 1.0f) * 5.5f;            // /h
  int   c  = (int)uf;  c = c > 10 ? 10 : c;
  float u  = uf - (float)c;
  float u2 = u * u, u3 = u2 * u, om = 1.0f - u;
  float w0 = om * om * om * (1.0f / 6.0f);
  float w1 = (3.0f * u3 - 6.0f * u2 + 4.0f) * (1.0f / 6.0f);
  float w2 = (-3.0f * u3 + 3.0f * u2 + 3.0f * u + 1.0f) * (1.0f / 6.0f);
  float w3 = u3 * (1.0f / 6.0f);
  uint32_t p01 = f2bf(w0) | (f2bf(w1) << 16);
  uint32_t p23 = f2bf(w2) | (f2bf(w3) << 16);
  uint64_t W = (uint64_t)p01 | ((uint64_t)p23 << 32);
  int d = c - 3;                            // slot of w0, in [-3, 7]
  uint64_t lo = (d < 0) ? (W >> ((-d) * 16))
              : ((d < 4) ? (W << (d * 16)) : 0ull);
  uint64_t hi = (d <= 0) ? 0ull
              : ((d < 4) ? (W >> ((4 - d) * 16)) : (W << ((d - 4) * 16)));
  o[0] = (uint32_t)lo; o[1] = (uint32_t)(lo >> 32);
  o[2] = (uint32_t)hi; o[3] = (uint32_t)(hi >> 32);
}

// ---------------- basis kernel: one (b,i) per thread, 16B store --------------
__global__ __launch_bounds__(256) void basis_kernel(const float* __restrict__ x,
                                                    __hip_bfloat16* __restrict__ A,
                                                    int total) {
  int idx = blockIdx.x * 256 + threadIdx.x;
  if (idx >= total) return;
  uint32_t o[4];
  basis_slots(x[idx], o);
  reinterpret_cast<int4*>(A)[idx] = make_int4(o[0], o[1], o[2], o[3]);
}

// ---------------- coeff cast: [512][512][8] fp32 -> bf16 (== B^T[512][4096]) --
__global__ __launch_bounds__(256) void cvt_kernel(const float* __restrict__ c,
                                                  __hip_bfloat16* __restrict__ Bt,
                                                  int total8) {
  int idx = blockIdx.x * 256 + threadIdx.x;
  if (idx >= total8) return;
  const float4* cp = reinterpret_cast<const float4*>(c) + (size_t)idx * 2;
  float4 a = cp[0], b = cp[1];
  union { unsigned short us[8]; int4 v; } pk;
  pk.us[0] = (unsigned short)f2bf(a.x); pk.us[1] = (unsigned short)f2bf(a.y);
  pk.us[2] = (unsigned short)f2bf(a.z); pk.us[3] = (unsigned short)f2bf(a.w);
  pk.us[4] = (unsigned short)f2bf(b.x); pk.us[5] = (unsigned short)f2bf(b.y);
  pk.us[6] = (unsigned short)f2bf(b.z); pk.us[7] = (unsigned short)f2bf(b.w);
  reinterpret_cast<int4*>(Bt)[idx] = pk.v;
}

// ---------------- GEMM: C[m,n] = sum_k A[m,k]*Bt[n,k] ------------------------
// 512 thr = 8 waves: kgrp = wid>>1 (K-quarter), waveN = wid&1.
// Wave tile 128x64 = 4x2 fragments of 32x32, K-step 16 (2 steps per BK=32).
__global__ __launch_bounds__(512) void gemm_kernel(
    const __hip_bfloat16* __restrict__ A,   // [8192][4096]
    const __hip_bfloat16* __restrict__ Bt,  // [512][4096]
    float* __restrict__ C) {                // [8192][512]
  __shared__ char lds[NGRP * GRP_LDS];      // 128 KB

  const int tid   = threadIdx.x;
  const int wid   = tid >> 6;               // 0..7
  const int lane  = tid & 63;
  const int l32   = lane & 31;
  const int lh    = lane >> 5;              // 0..1: k-half within fragment
  const int kgrp  = wid >> 1;               // 0..3: K-quarter
  const int waveN = wid & 1;                // 0..1: N-half (64 cols)
  const int tg    = tid & 127;              // thread-in-group

  // XCD decode: each XCD owns 8 M-stripes x all 4 N-tiles; Bt (4MB) stays
  // L2-resident per XCD, A-stripes stream through once.
  const int b  = blockIdx.x;
  const int q  = b >> 3;                    // 0..31
  const int mt = (b & 7) * 8 + (q >> 2);    // 0..63
  const int nt = q & 3;                     // 0..3
  const int m0 = mt * BM;
  const int n0 = nt * BN;

  char* grp = lds + kgrp * GRP_LDS;

  // staging: phys slot s (512 per A- or B-half) -> logical (row r, chunk c):
  // L = s>>3, sl = s&7; u = sl ^ (L&7) ^ (((L>>3)&1)<<2); r = 2L+(u>>2), c=u&3
  uint32_t aGlob[4], bGlob[4], sOff[4];
#pragma unroll
  for (int t = 0; t < 4; ++t) {
    int s  = t * 128 + tg;                  // 0..511
    int L  = s >> 3, sl = s & 7;
    int u  = sl ^ (L & 7) ^ (((L >> 3) & 1) << 2);
    int r  = 2 * L + (u >> 2);
    int c  = u & 3;
    sOff[t]  = (uint32_t)s * 16u;
    aGlob[t] = (uint32_t)(m0 + r) * K_DIM + (uint32_t)c * 8u
             + (uint32_t)kgrp * 1024u;
    bGlob[t] = (uint32_t)(n0 + r) * K_DIM + (uint32_t)c * 8u
             + (uint32_t)kgrp * 1024u;
  }

  // fragment read offsets (A at +0, B at +8KB).  32x32x16 operand layout:
  // lane holds row = lane&31 (+frag base), k = lh*8 + j -> chunk c = ks*2+lh.
  uint32_t aOff[2][4], bOff[2][2];
#pragma unroll
  for (int ks = 0; ks < 2; ++ks) {
    int c = ks * 2 + lh;
#pragma unroll
    for (int mi = 0; mi < 4; ++mi) {
      int r = mi * 32 + l32;
      aOff[ks][mi] = (uint32_t)((r >> 1) * 8 + swz32(r, c)) * 16u;
    }
#pragma unroll
    for (int ni = 0; ni < 2; ++ni) {
      int r = waveN * 64 + ni * 32 + l32;
      bOff[ks][ni] = 8192u + (uint32_t)((r >> 1) * 8 + swz32(r, c)) * 16u;
    }
  }

  f32x16 acc[4][2];
#pragma unroll
  for (int mi = 0; mi < 4; ++mi)
#pragma unroll
    for (int ni = 0; ni < 2; ++ni)
      acc[mi][ni] = (f32x16){0.f};

  // prologue: stage tile 0 of this K-quarter into buffer 0
#pragma unroll
  for (int t = 0; t < 4; ++t) {
    gload_lds16(A + aGlob[t], grp + sOff[t]);
    gload_lds16(Bt + bGlob[t], grp + 8192 + sOff[t]);
  }

  for (int it = 0; it < NT_G; ++it) {
    char* bufc = grp + (it & 1) * BUF_SZ;
    __syncthreads();                        // staging for tile it drained
    if (it + 1 < NT_G) {                    // stage it+1 under compute of it
      char* bufn = grp + ((it + 1) & 1) * BUF_SZ;
      uint32_t kt = (uint32_t)(it + 1) * BK;
#pragma unroll
      for (int t = 0; t < 4; ++t) {
        gload_lds16(A + aGlob[t] + kt, bufn + sOff[t]);
        gload_lds16(Bt + bGlob[t] + kt, bufn + 8192 + sOff[t]);
      }
    }
#pragma unroll
    for (int ks = 0; ks < 2; ++ks) {
      short8 af[4], bf[2];
#pragma unroll
      for (int mi = 0; mi < 4; ++mi)
        af[mi] = *reinterpret_cast<const short8*>(bufc + aOff[ks][mi]);
#pragma unroll
      for (int ni = 0; ni < 2; ++ni)
        bf[ni] = *reinterpret_cast<const short8*>(bufc + bOff[ks][ni]);
#pragma unroll
      for (int mi = 0; mi < 4; ++mi)
#pragma unroll
        for (int ni = 0; ni < 2; ++ni)
          acc[mi][ni] = __builtin_amdgcn_mfma_f32_32x32x16_bf16(
              af[mi], bf[ni], acc[mi][ni], 0, 0, 0);
    }
  }

  // ---- 4-way split-K tree reduce in LDS, then group 0 stores --------------
  // Park layout per parking group: waveN*32KB + ((mi*2+ni)*4+j)*1024 + lane*16
  __syncthreads();
  if (kgrp & 1) {                           // groups 1,3 park
    char* dst = lds + (kgrp >> 1) * 65536 + waveN * 32768;
#pragma unroll
    for (int mi = 0; mi < 4; ++mi)
#pragma unroll
      for (int ni = 0; ni < 2; ++ni)
#pragma unroll
        for (int j = 0; j < 4; ++j) {
          f32x4 v;
#pragma unroll
          for (int rr = 0; rr < 4; ++rr) v[rr] = acc[mi][ni][j * 4 + rr];
          *reinterpret_cast<f32x4*>(
              dst + ((mi * 2 + ni) * 4 + j) * 1024 + lane * 16) = v;
        }
  }
  __syncthreads();
  if (!(kgrp & 1)) {                        // groups 0,2 add partner
    char* src = lds + (kgrp >> 1) * 65536 + waveN * 32768;
#pragma unroll
    for (int mi = 0; mi < 4; ++mi)
#pragma unroll
      for (int ni = 0; ni < 2; ++ni)
#pragma unroll
        for (int j = 0; j < 4; ++j) {
          f32x4 o = *reinterpret_cast<f32x4*>(
              src + ((mi * 2 + ni) * 4 + j) * 1024 + lane * 16);
#pragma unroll
          for (int rr = 0; rr < 4; ++rr) acc[mi][ni][j * 4 + rr] += o[rr];
        }
  }
  __syncthreads();
  if (kgrp == 2) {                          // group 2 parks its sum
    char* dst = lds + waveN * 32768;
#pragma unroll
    for (int mi = 0; mi < 4; ++mi)
#pragma unroll
      for (int ni = 0; ni < 2; ++ni)
#pragma unroll
        for (int j = 0; j < 4; ++j) {
          f32x4 v;
#pragma unroll
          for (int rr = 0; rr < 4; ++rr) v[rr] = acc[mi][ni][j * 4 + rr];
          *reinterpret_cast<f32x4*>(
              dst + ((mi * 2 + ni) * 4 + j) * 1024 + lane * 16) = v;
        }
  }
  __syncthreads();
  if (kgrp == 0) {                          // group 0: final add + store
    char* src = lds + waveN * 32768;
#pragma unroll
    for (int mi = 0; mi < 4; ++mi) {
#pragma unroll
      for (int ni = 0; ni < 2; ++ni) {
        int col   = n0 + waveN * 64 + ni * 32 + l32;
        int rbase = m0 + mi * 32 + lh * 4;
#pragma unroll
        for (int j = 0; j < 4; ++j) {
          f32x4 o = *reinterpret_cast<f32x4*>(
              src + ((mi * 2 + ni) * 4 + j) * 1024 + lane * 16);
#pragma unroll
          for (int rr = 0; rr < 4; ++rr) {
            int row = rbase + 8 * j + rr;       // m74/m101 C/D layout
            C[(size_t)row * N_DIM + col] = acc[mi][ni][j * 4 + rr] + o[rr];
          }
        }
      }
    }
  }
}

extern "C" void kernel_launch(void* const* d_in, const int* in_sizes, int n_in,
                              void* d_out, int out_size, void* d_ws, size_t ws_size,
                              hipStream_t stream) {
  const float* x    = (const float*)d_in[0];   // [8192,512]
  const float* coef = (const float*)d_in[1];   // [512,512,8]
  float* out = (float*)d_out;                  // [8192,512]

  __hip_bfloat16* Bt = (__hip_bfloat16*)d_ws;                       // 4 MB
  __hip_bfloat16* A  = (__hip_bfloat16*)((char*)d_ws + (size_t)4 * 1024 * 1024);
  // A = 64 MB; ws is ~268 MB (observed via harness poison fill), fits.

  const int total8 = N_DIM * K_DIM / 8;        // 262144
  cvt_kernel<<<(total8 + 255) / 256, 256, 0, stream>>>(coef, Bt, total8);

  const int total = M_TOTAL * 512;             // (b,i) pairs
  basis_kernel<<<total / 256, 256, 0, stream>>>(x, A, total);

  gemm_kernel<<<(M_TOTAL / BM) * (N_DIM / BN), 512, 0, stream>>>(A, Bt, out);
}

// Round 8
// 129.928 us; speedup vs baseline: 1.0067x; 1.0067x over previous
//
#include <hip/hip_runtime.h>
#include <hip/hip_bf16.h>
#include <stdint.h>

// KAN layer: out[b,o] = sum_{i,k} basis(tanh(x[b,i]))[k] * coeffs[o,i,k]
// GEMM M=8192, N=512, K=4096.  cvt coeffs->Bt bf16 ; basis(x)->A bf16 ;
// gemm(A,Bt)->partials[4] ; reduce(partials)->out.
// R13 post-mortem: LDS-volume theory falsified (fewer bytes, slower).  The
// 128^2/2-barrier family ceilings at ~900TF (m233: ~72% of 2-phase time is
// stage+vmcnt+barrier overhead).  Escape = 256^2 8-phase counted-vmcnt
// schedule (T2+T3+T4+T5, 1563TF proven).  N=512 only gives 64 such tiles,
// so: block-split-K x4 -> grid 256 = 32mt x 2nt x 4splits, f32 partials in
// ws + tiny reduce kernel.
// R14 was this kernel with a precedence bug (ptr + 4 << 20); fixed here.
// Schedule per K-tile (BK=64, 16 tiles/block): 4 phases, each
//   {8x ds_read (R7-proven c^(row&7) swizzle) | 2x global_load_lds issue |
//    counted vmcnt(2) at phases 0&3 only | s_barrier | setprio(1) 16 MFMA
//    setprio(0) | s_barrier}
// Issue order B g0..g3 then A rows {0-63,128-191,64-127,192-255} makes every
// phase's operand group strictly older than the vmcnt(2) allowance (checked
// for prologue / steady state / last tile).  Raw s_barrier everywhere in the
// loop -- no __syncthreads vmcnt(0) drain.

#define M_TOTAL 8192
#define N_DIM   512
#define K_DIM   4096
#define BM 256
#define BN 256
#define BK 64
#define NSPLIT 4
#define NT 16               // K-tiles per block: 1024/64
#define BUF_SZ 65536        // A 32KB + B 32KB

typedef __attribute__((ext_vector_type(8))) short short8;    // 8 x bf16
typedef __attribute__((ext_vector_type(4))) float f32x4;

typedef const __attribute__((address_space(1))) uint32_t ga_u32;
typedef __attribute__((address_space(3))) uint32_t ls_u32;

__device__ __forceinline__ void gload_lds16(const void* g, void* l) {
  // async global->LDS, 16B/lane; LDS dest = wave-uniform base + lane*16
  __builtin_amdgcn_global_load_lds((ga_u32*)(uintptr_t)g,
                                   (ls_u32*)(uint32_t)(uintptr_t)l, 16, 0, 0);
}

__device__ __forceinline__ uint32_t f2bf(float f) {
  uint32_t u = __builtin_bit_cast(uint32_t, f);
  return (u + 0x7FFFu + ((u >> 16) & 1u)) >> 16;
}

// cardinal cubic B-spline on uniform knots h=2/11; t=tanh(x) in (-1,1).
// 8 basis slots as 4xu32 packed bf16: w0..w3 land at slots c-3..c, rest 0.
__device__ __forceinline__ void basis_slots(float xv, uint32_t o[4]) {
  xv = fminf(15.f, fmaxf(-15.f, xv));
  float e  = __expf(2.0f * xv);
  float t  = (e - 1.0f) * __builtin_amdgcn_rcpf(e + 1.0f);
  float uf = (t + 1.0f) * 5.5f;            // /h
  int   c  = (int)uf;  c = c > 10 ? 10 : c;
  float u  = uf - (float)c;
  float u2 = u * u, u3 = u2 * u, om = 1.0f - u;
  float w0 = om * om * om * (1.0f / 6.0f);
  float w1 = (3.0f * u3 - 6.0f * u2 + 4.0f) * (1.0f / 6.0f);
  float w2 = (-3.0f * u3 + 3.0f * u2 + 3.0f * u + 1.0f) * (1.0f / 6.0f);
  float w3 = u3 * (1.0f / 6.0f);
  uint32_t p01 = f2bf(w0) | (f2bf(w1) << 16);
  uint32_t p23 = f2bf(w2) | (f2bf(w3) << 16);
  uint64_t W = (uint64_t)p01 | ((uint64_t)p23 << 32);
  int d = c - 3;                            // slot of w0, in [-3, 7]
  uint64_t lo = (d < 0) ? (W >> ((-d) * 16))
              : ((d < 4) ? (W << (d * 16)) : 0ull);
  uint64_t hi = (d <= 0) ? 0ull
              : ((d < 4) ? (W >> ((4 - d) * 16)) : (W << ((d - 4) * 16)));
  o[0] = (uint32_t)lo; o[1] = (uint32_t)(lo >> 32);
  o[2] = (uint32_t)hi; o[3] = (uint32_t)(hi >> 32);
}

// ---------------- basis kernel: one (b,i) per thread, 16B store --------------
__global__ __launch_bounds__(256) void basis_kernel(const float* __restrict__ x,
                                                    __hip_bfloat16* __restrict__ A,
                                                    int total) {
  int idx = blockIdx.x * 256 + threadIdx.x;
  if (idx >= total) return;
  uint32_t o[4];
  basis_slots(x[idx], o);
  reinterpret_cast<int4*>(A)[idx] = make_int4(o[0], o[1], o[2], o[3]);
}

// ---------------- coeff cast: [512][512][8] fp32 -> bf16 (== B^T[512][4096]) --
__global__ __launch_bounds__(256) void cvt_kernel(const float* __restrict__ c,
                                                  __hip_bfloat16* __restrict__ Bt,
                                                  int total8) {
  int idx = blockIdx.x * 256 + threadIdx.x;
  if (idx >= total8) return;
  const float4* cp = reinterpret_cast<const float4*>(c) + (size_t)idx * 2;
  float4 a = cp[0], b = cp[1];
  union { unsigned short us[8]; int4 v; } pk;
  pk.us[0] = (unsigned short)f2bf(a.x); pk.us[1] = (unsigned short)f2bf(a.y);
  pk.us[2] = (unsigned short)f2bf(a.z); pk.us[3] = (unsigned short)f2bf(a.w);
  pk.us[4] = (unsigned short)f2bf(b.x); pk.us[5] = (unsigned short)f2bf(b.y);
  pk.us[6] = (unsigned short)f2bf(b.z); pk.us[7] = (unsigned short)f2bf(b.w);
  reinterpret_cast<int4*>(Bt)[idx] = pk.v;
}

// ---------------- GEMM: P[split][m,n] = sum_{k in split} A[m,k]*Bt[n,k] -----
// 512 thr = 8 waves (2M x 4N), wave tile 128x64 = 8x4 frags of 16x16, BK=64.
__global__ __launch_bounds__(512, 2) void gemm_kernel(
    const __hip_bfloat16* __restrict__ A,   // [8192][4096]
    const __hip_bfloat16* __restrict__ Bt,  // [512][4096]
    float* __restrict__ P) {                // [4][8192][512] partials
  __shared__ char lds[2 * BUF_SZ];          // 128 KB

  const int tid   = threadIdx.x;
  const int wid   = tid >> 6;               // 0..7
  const int lane  = tid & 63;
  const int quad  = lane >> 4;
  const int l16   = lane & 15;
  const int waveM = wid >> 2;               // 0..1 (128 rows each)
  const int waveN = wid & 3;                // 0..3 (64 cols each)

  // decode: xcd-major so each XCD owns 4 mt x 2 nt x 4 splits.  A-stripe
  // (4x2MB) streams once per XCD; Bt slices stay L2-resident.
  const int b     = blockIdx.x;             // 0..255
  const int xcd   = b & 7;
  const int r     = b >> 3;                 // 0..31
  const int mt    = xcd * 4 + (r >> 3);     // 0..31
  const int q     = r & 7;
  const int nt    = q & 1;                  // 0..1
  const int split = q >> 1;                 // 0..3
  const int m0 = mt * BM;
  const int n0 = nt * BN;
  const uint32_t kb = (uint32_t)split * 1024u;

  // ---- staging descriptors: 8 loads/thread/K-tile (4 B-groups, 4 A-groups).
  // A-load t covers rows {0,128,64,192}+0..63 so that groups needed first are
  // issued first; slot = row*8 + p, source chunk cc = p ^ (row&7) (rule #21).
  uint32_t aSrc[4], aDst[4], bSrc[4], bDst[4];
#pragma unroll
  for (int t = 0; t < 4; ++t) {
    int p    = tid & 7;
    int arow = ((t & 1) << 7) + ((t >> 1) << 6) + (tid >> 3);
    aSrc[t] = (uint32_t)(m0 + arow) * K_DIM + (uint32_t)((p ^ (arow & 7)) * 8)
            + kb;
    aDst[t] = (uint32_t)(arow * 8 + p) * 16u;
    int brow = t * 64 + (tid >> 3);
    bSrc[t] = (uint32_t)(n0 + brow) * K_DIM + (uint32_t)((p ^ (brow & 7)) * 8)
            + kb;
    bDst[t] = 32768u + (uint32_t)(brow * 8 + p) * 16u;
  }

  // ---- fragment read offsets (A at +0, B at +32KB), R7-proven swizzle
  uint32_t aOff[2][2][4], bOff[2][4];
#pragma unroll
  for (int kk = 0; kk < 2; ++kk) {
    int c = kk * 4 + quad;
#pragma unroll
    for (int mh = 0; mh < 2; ++mh)
#pragma unroll
      for (int mi = 0; mi < 4; ++mi) {
        int row = waveM * 128 + mh * 64 + mi * 16 + l16;
        aOff[kk][mh][mi] = (uint32_t)(row * 8 + (c ^ (row & 7))) * 16u;
      }
#pragma unroll
    for (int ni = 0; ni < 4; ++ni) {
      int row = waveN * 64 + ni * 16 + l16;
      bOff[kk][ni] = 32768u + (uint32_t)(row * 8 + (c ^ (row & 7))) * 16u;
    }
  }

  f32x4 acc[2][4][4];                       // [mh][mi][ni]
#pragma unroll
  for (int mh = 0; mh < 2; ++mh)
#pragma unroll
    for (int mi = 0; mi < 4; ++mi)
#pragma unroll
      for (int ni = 0; ni < 4; ++ni)
        acc[mh][mi][ni] = (f32x4){0.f, 0.f, 0.f, 0.f};

  // ---- prologue: stage tile 0 into buf0 (B then A; A t2,t3 are the 2 newest)
#pragma unroll
  for (int t = 0; t < 4; ++t) gload_lds16(Bt + bSrc[t], lds + bDst[t]);
#pragma unroll
  for (int t = 0; t < 4; ++t) gload_lds16(A + aSrc[t], lds + aDst[t]);
  asm volatile("s_waitcnt vmcnt(2)" ::: "memory");
  __builtin_amdgcn_s_barrier();

  for (int it = 0; it < NT; ++it) {
    char* bufc = lds + (it & 1) * BUF_SZ;
    char* bufn = lds + ((it + 1) & 1) * BUF_SZ;
    const uint32_t kt = (uint32_t)(it + 1) * BK;
    const bool more = (it + 1) < NT;
    short8 af[4], bfr[4];

    // ===== phase 0: kk=0, mh=0 =====
#pragma unroll
    for (int mi = 0; mi < 4; ++mi)
      af[mi] = *reinterpret_cast<const short8*>(bufc + aOff[0][0][mi]);
#pragma unroll
    for (int ni = 0; ni < 4; ++ni)
      bfr[ni] = *reinterpret_cast<const short8*>(bufc + bOff[0][ni]);
    if (more) {
      gload_lds16(Bt + bSrc[0] + kt, bufn + bDst[0]);
      gload_lds16(Bt + bSrc[1] + kt, bufn + bDst[1]);
      asm volatile("s_waitcnt vmcnt(2)" ::: "memory");  // A(it) g1,g3 landed
    } else {
      asm volatile("s_waitcnt vmcnt(0)" ::: "memory");
    }
    __builtin_amdgcn_s_barrier();
    __builtin_amdgcn_s_setprio(1);
#pragma unroll
    for (int mi = 0; mi < 4; ++mi)
#pragma unroll
      for (int ni = 0; ni < 4; ++ni)
        acc[0][mi][ni] = __builtin_amdgcn_mfma_f32_16x16x32_bf16(
            af[mi], bfr[ni], acc[0][mi][ni], 0, 0, 0);
    __builtin_amdgcn_s_setprio(0);
    __builtin_amdgcn_s_barrier();

    // ===== phase 1: kk=0, mh=1 (B frags reused) =====
#pragma unroll
    for (int mi = 0; mi < 4; ++mi)
      af[mi] = *reinterpret_cast<const short8*>(bufc + aOff[0][1][mi]);
    if (more) {
      gload_lds16(Bt + bSrc[2] + kt, bufn + bDst[2]);
      gload_lds16(Bt + bSrc[3] + kt, bufn + bDst[3]);
    }
    __builtin_amdgcn_s_barrier();
    __builtin_amdgcn_s_setprio(1);
#pragma unroll
    for (int mi = 0; mi < 4; ++mi)
#pragma unroll
      for (int ni = 0; ni < 4; ++ni)
        acc[1][mi][ni] = __builtin_amdgcn_mfma_f32_16x16x32_bf16(
            af[mi], bfr[ni], acc[1][mi][ni], 0, 0, 0);
    __builtin_amdgcn_s_setprio(0);
    __builtin_amdgcn_s_barrier();

    // ===== phase 2: kk=1, mh=0 =====
#pragma unroll
    for (int mi = 0; mi < 4; ++mi)
      af[mi] = *reinterpret_cast<const short8*>(bufc + aOff[1][0][mi]);
#pragma unroll
    for (int ni = 0; ni < 4; ++ni)
      bfr[ni] = *reinterpret_cast<const short8*>(bufc + bOff[1][ni]);
    if (more) {
      gload_lds16(A + aSrc[0] + kt, bufn + aDst[0]);
      gload_lds16(A + aSrc[1] + kt, bufn + aDst[1]);
    }
    __builtin_amdgcn_s_barrier();
    __builtin_amdgcn_s_setprio(1);
#pragma unroll
    for (int mi = 0; mi < 4; ++mi)
#pragma unroll
      for (int ni = 0; ni < 4; ++ni)
        acc[0][mi][ni] = __builtin_amdgcn_mfma_f32_16x16x32_bf16(
            af[mi], bfr[ni], acc[0][mi][ni], 0, 0, 0);
    __builtin_amdgcn_s_setprio(0);
    __builtin_amdgcn_s_barrier();

    // ===== phase 3: kk=1, mh=1 =====
#pragma unroll
    for (int mi = 0; mi < 4; ++mi)
      af[mi] = *reinterpret_cast<const short8*>(bufc + aOff[1][1][mi]);
    if (more) {
      gload_lds16(A + aSrc[2] + kt, bufn + aDst[2]);
      gload_lds16(A + aSrc[3] + kt, bufn + aDst[3]);
      asm volatile("s_waitcnt vmcnt(2)" ::: "memory");  // B(it+1)+A g0,g2 in
    }
    __builtin_amdgcn_s_barrier();
    __builtin_amdgcn_s_setprio(1);
#pragma unroll
    for (int mi = 0; mi < 4; ++mi)
#pragma unroll
      for (int ni = 0; ni < 4; ++ni)
        acc[1][mi][ni] = __builtin_amdgcn_mfma_f32_16x16x32_bf16(
            af[mi], bfr[ni], acc[1][mi][ni], 0, 0, 0);
    __builtin_amdgcn_s_setprio(0);
    __builtin_amdgcn_s_barrier();
  }

  // ---- epilogue: store f32 partial tile (no LDS reduce; reduce kernel sums)
  float* Pb = P + (size_t)split * M_TOTAL * N_DIM;
#pragma unroll
  for (int mh = 0; mh < 2; ++mh)
#pragma unroll
    for (int mi = 0; mi < 4; ++mi) {
#pragma unroll
      for (int ni = 0; ni < 4; ++ni) {
        int col  = n0 + waveN * 64 + ni * 16 + l16;
        int rowb = m0 + waveM * 128 + mh * 64 + mi * 16 + quad * 4;
#pragma unroll
        for (int rr = 0; rr < 4; ++rr)       // m89/m91 C/D layout
          Pb[(size_t)(rowb + rr) * N_DIM + col] = acc[mh][mi][ni][rr];
      }
    }
}

// ---------------- reduce: out = sum of 4 partials (f32x4 grid-stride) -------
__global__ __launch_bounds__(256) void reduce_kernel(
    const f32x4* __restrict__ P, f32x4* __restrict__ C, int n4) {
  const int stride = gridDim.x * 256;
  for (int i = blockIdx.x * 256 + threadIdx.x; i < n4; i += stride) {
    f32x4 v = P[i] + P[n4 + i] + P[2 * n4 + i] + P[3 * n4 + i];
    C[i] = v;
  }
}

extern "C" void kernel_launch(void* const* d_in, const int* in_sizes, int n_in,
                              void* d_out, int out_size, void* d_ws, size_t ws_size,
                              hipStream_t stream) {
  const float* x    = (const float*)d_in[0];   // [8192,512]
  const float* coef = (const float*)d_in[1];   // [512,512,8]
  float* out = (float*)d_out;                  // [8192,512]

  __hip_bfloat16* Bt = (__hip_bfloat16*)d_ws;                        // 4 MB
  __hip_bfloat16* A  = (__hip_bfloat16*)((char*)d_ws + ((size_t)4 << 20));
  float*          Pp = (float*)((char*)d_ws + ((size_t)68 << 20));   // 64 MB
  // ws usage: 4 + 64 + 64 = 132 MB; ws is ~268 MB, fits.

  const int total8 = N_DIM * K_DIM / 8;        // 262144
  cvt_kernel<<<(total8 + 255) / 256, 256, 0, stream>>>(coef, Bt, total8);

  const int total = M_TOTAL * 512;             // (b,i) pairs
  basis_kernel<<<total / 256, 256, 0, stream>>>(x, A, total);

  gemm_kernel<<<256, 512, 0, stream>>>(A, Bt, Pp);

  const int n4 = M_TOTAL * N_DIM / 4;          // 1048576
  reduce_kernel<<<2048, 256, 0, stream>>>((const f32x4*)Pp, (f32x4*)out, n4);
}